// Round 7
// baseline (644.217 us; speedup 1.0000x reference)
//
#include <hip/hip_runtime.h>
#include <stdint.h>

typedef __bf16 bf16;
typedef __bf16 bfx8 __attribute__((ext_vector_type(8)));
typedef __bf16 bfx4 __attribute__((ext_vector_type(4)));
typedef float floatx4 __attribute__((ext_vector_type(4)));

#define B_ 2
#define S_ 2048
#define DIM_ 2048
#define H_ 16
#define DK_ 128
#define DR_ 64
#define DC_ 512
#define DCP_ 1024
#define DV_ 128
#define DQK_ 192
#define DVP_ 144   // V^T rows padded: 128 data + ones row (128) + zeros (129..143)

#define MASK_VAL (-30000.0f)
#define C1_ 0.10411754f   // (1/sqrt(192)) * log2(e), folded into q at G2

// ----------------------------------------------------------------------------
// Batched transpose + downcast: in f32 [Hb][K][N] -> out bf16 [Hb][N][K]
// ----------------------------------------------------------------------------
__global__ void k_transpose(const float* __restrict__ in, bf16* __restrict__ out,
                            int K, int N) {
    __shared__ float tile[32][33];
    int h = blockIdx.z;
    int n0 = blockIdx.x * 32, k0 = blockIdx.y * 32;
    const float* ip = in + (size_t)h * K * N;
    bf16* op = out + (size_t)h * K * N;
    int tx = threadIdx.x & 31, ty = threadIdx.x >> 5;
#pragma unroll
    for (int i = 0; i < 32; i += 8)
        tile[ty + i][tx] = ip[(size_t)(k0 + ty + i) * N + (n0 + tx)];
    __syncthreads();
#pragma unroll
    for (int i = 0; i < 32; i += 8)
        op[(size_t)(n0 + ty + i) * K + (k0 + tx)] = (bf16)tile[tx][ty + i];
}

// Fill V^T pad rows: row 128 = 1.0 (row-sum column), rows 129..143 = 0.
__global__ void k_vinit(bf16* __restrict__ vt_ws) {
    int idx = blockIdx.x * 256 + threadIdx.x;   // over 32 bh * 16 rows * 2048
    for (; idx < B_ * H_ * 16 * S_; idx += gridDim.x * 256) {
        int bh = idx / (16 * S_);
        int rem = idx - bh * 16 * S_;
        int row = 128 + (rem / S_);
        int s = rem & (S_ - 1);
        vt_ws[((size_t)bh * DVP_ + row) * S_ + s] = (bf16)(row == 128 ? 1.f : 0.f);
    }
}

// ----------------------------------------------------------------------------
// 8-element row loaders (convert to bf16 if source is f32)
// ----------------------------------------------------------------------------
__device__ __forceinline__ bfx8 load8(const bf16* p) { return *(const bfx8*)p; }
__device__ __forceinline__ bfx8 load8(const float* p) {
    float4 a = *(const float4*)p;
    float4 b = *(const float4*)(p + 4);
    bfx8 r;
    r[0] = (bf16)a.x; r[1] = (bf16)a.y; r[2] = (bf16)a.z; r[3] = (bf16)a.w;
    r[4] = (bf16)b.x; r[5] = (bf16)b.y; r[6] = (bf16)b.z; r[7] = (bf16)b.w;
    return r;
}

// ----------------------------------------------------------------------------
// GEMM core: C[128x128] tile of A[M,K] @ Bt[N,K]^T, f32 acc.
// ----------------------------------------------------------------------------
#define LSTR 40

template <typename TA>
__device__ __forceinline__ void gemm_core(const TA* __restrict__ A,
                                          const bf16* __restrict__ Bt,
                                          int K, int rowlimB,
                                          floatx4 acc[4][4],
                                          bf16* A_lds, bf16* B_lds) {
    int tid = threadIdx.x;
    int wave = tid >> 6, lane = tid & 63;
    int l15 = lane & 15, quad = lane >> 4;
    int wm = (wave & 1) * 64, wn = (wave >> 1) * 64;
    int r0 = tid >> 2;
    int c0 = (tid & 3) * 8;
    int rb0 = r0 <= rowlimB ? r0 : rowlimB;
    int rb1 = (r0 + 64) <= rowlimB ? (r0 + 64) : rowlimB;
    for (int k0 = 0; k0 < K; k0 += 32) {
        bfx8 ra0 = load8(A + (size_t)r0 * K + k0 + c0);
        bfx8 ra1 = load8(A + (size_t)(r0 + 64) * K + k0 + c0);
        bfx8 vb0 = load8(Bt + (size_t)rb0 * K + k0 + c0);
        bfx8 vb1 = load8(Bt + (size_t)rb1 * K + k0 + c0);
        __syncthreads();
        *(bfx8*)(A_lds + r0 * LSTR + c0) = ra0;
        *(bfx8*)(A_lds + (r0 + 64) * LSTR + c0) = ra1;
        *(bfx8*)(B_lds + r0 * LSTR + c0) = vb0;
        *(bfx8*)(B_lds + (r0 + 64) * LSTR + c0) = vb1;
        __syncthreads();
        bfx8 a[4], b[4];
#pragma unroll
        for (int t = 0; t < 4; ++t)
            a[t] = *(const bfx8*)(A_lds + (wm + t * 16 + l15) * LSTR + quad * 8);
#pragma unroll
        for (int t = 0; t < 4; ++t)
            b[t] = *(const bfx8*)(B_lds + (wn + t * 16 + l15) * LSTR + quad * 8);
#pragma unroll
        for (int mt = 0; mt < 4; ++mt)
#pragma unroll
            for (int nt = 0; nt < 4; ++nt)
                acc[mt][nt] = __builtin_amdgcn_mfma_f32_16x16x32_bf16(
                    a[mt], b[nt], acc[mt][nt], 0, 0, 0);
    }
}

// G1: x(f32) -> {c, cp, k_r} (bf16).  grid (13, 32)
__global__ __launch_bounds__(256, 2) void k_gemm1(
    const float* __restrict__ x, const bf16* __restrict__ Wt_c,
    const bf16* __restrict__ Wt_cp, const bf16* __restrict__ Wt_kr,
    bf16* __restrict__ c_ws, bf16* __restrict__ cp_ws, bf16* __restrict__ kr_ws) {
    __shared__ __attribute__((aligned(16))) bf16 A_lds[128 * LSTR];
    __shared__ __attribute__((aligned(16))) bf16 B_lds[128 * LSTR];
    int bx = blockIdx.x, by = blockIdx.y;
    const bf16* Bt; bf16* outp; int ldc, col0, rowlim;
    if (bx < 4)       { Bt = Wt_c  + (size_t)bx * 128 * DIM_;       outp = c_ws;  ldc = DC_;  col0 = bx * 128;       rowlim = 127; }
    else if (bx < 12) { Bt = Wt_cp + (size_t)(bx - 4) * 128 * DIM_; outp = cp_ws; ldc = DCP_; col0 = (bx - 4) * 128; rowlim = 127; }
    else              { Bt = Wt_kr;                                  outp = kr_ws; ldc = DR_;  col0 = 0;              rowlim = 63;  }
    floatx4 acc[4][4];
#pragma unroll
    for (int i = 0; i < 4; ++i)
#pragma unroll
        for (int j = 0; j < 4; ++j) acc[i][j] = (floatx4){0.f, 0.f, 0.f, 0.f};
    gemm_core(x + (size_t)by * 128 * DIM_, Bt, DIM_, rowlim, acc, A_lds, B_lds);
    int tid = threadIdx.x, wave = tid >> 6, lane = tid & 63;
    int l15 = lane & 15, quad = lane >> 4;
    int wm = (wave & 1) * 64, wn = (wave >> 1) * 64;
#pragma unroll
    for (int mt = 0; mt < 4; ++mt)
#pragma unroll
        for (int nt = 0; nt < 4; ++nt) {
            int n = wn + nt * 16 + l15;
            if (n > rowlim) continue;
#pragma unroll
            for (int r = 0; r < 4; ++r) {
                int m = by * 128 + wm + mt * 16 + quad * 4 + r;
                outp[(size_t)m * ldc + col0 + n] = (bf16)acc[mt][nt][r];
            }
        }
}

// G2: cp -> q*C1 (q_c cols 0..127, q_r cols 128..191), per head. grid (2, 32, 16)
__global__ __launch_bounds__(256, 2) void k_gemm2(
    const bf16* __restrict__ cp_ws, const bf16* __restrict__ Wt_qc,
    const bf16* __restrict__ Wt_qr, bf16* __restrict__ q_ws) {
    __shared__ __attribute__((aligned(16))) bf16 A_lds[128 * LSTR];
    __shared__ __attribute__((aligned(16))) bf16 B_lds[128 * LSTR];
    int bx = blockIdx.x, by = blockIdx.y, h = blockIdx.z;
    const bf16* Bt; int col0, rowlim;
    if (bx == 0) { Bt = Wt_qc + (size_t)h * DK_ * DCP_; col0 = 0;   rowlim = 127; }
    else         { Bt = Wt_qr + (size_t)h * DR_ * DCP_; col0 = 128; rowlim = 63;  }
    floatx4 acc[4][4];
#pragma unroll
    for (int i = 0; i < 4; ++i)
#pragma unroll
        for (int j = 0; j < 4; ++j) acc[i][j] = (floatx4){0.f, 0.f, 0.f, 0.f};
    gemm_core(cp_ws + (size_t)by * 128 * DCP_, Bt, DCP_, rowlim, acc, A_lds, B_lds);
    int tid = threadIdx.x, wave = tid >> 6, lane = tid & 63;
    int l15 = lane & 15, quad = lane >> 4;
    int wm = (wave & 1) * 64, wn = (wave >> 1) * 64;
#pragma unroll
    for (int mt = 0; mt < 4; ++mt)
#pragma unroll
        for (int nt = 0; nt < 4; ++nt) {
            int n = wn + nt * 16 + l15;
            if (n > rowlim) continue;
#pragma unroll
            for (int r = 0; r < 4; ++r) {
                int m = by * 128 + wm + mt * 16 + quad * 4 + r;
                int b = m >> 11, s = m & 2047;
                q_ws[(((size_t)b * H_ + h) * S_ + s) * DQK_ + col0 + n] =
                    (bf16)(acc[mt][nt][r] * C1_);
            }
        }
}

// G3: c -> {k_c [B,H,S,128], v^T [B,H,DVP,S] rows 0..127}, per head. grid (2,32,16)
__global__ __launch_bounds__(256, 2) void k_gemm3(
    const bf16* __restrict__ c_ws, const bf16* __restrict__ Wt_kc,
    const bf16* __restrict__ Wt_v, bf16* __restrict__ kc_ws, bf16* __restrict__ vt_ws) {
    __shared__ __attribute__((aligned(16))) bf16 A_lds[128 * LSTR];
    __shared__ __attribute__((aligned(16))) bf16 B_lds[128 * LSTR];
    int bx = blockIdx.x, by = blockIdx.y, h = blockIdx.z;
    const bf16* Bt = (bx == 0) ? (Wt_kc + (size_t)h * DK_ * DC_)
                               : (Wt_v  + (size_t)h * DV_ * DC_);
    floatx4 acc[4][4];
#pragma unroll
    for (int i = 0; i < 4; ++i)
#pragma unroll
        for (int j = 0; j < 4; ++j) acc[i][j] = (floatx4){0.f, 0.f, 0.f, 0.f};
    gemm_core(c_ws + (size_t)by * 128 * DC_, Bt, DC_, 127, acc, A_lds, B_lds);
    int tid = threadIdx.x, wave = tid >> 6, lane = tid & 63;
    int l15 = lane & 15, quad = lane >> 4;
    int wm = (wave & 1) * 64, wn = (wave >> 1) * 64;
#pragma unroll
    for (int mt = 0; mt < 4; ++mt)
#pragma unroll
        for (int nt = 0; nt < 4; ++nt) {
            int n = wn + nt * 16 + l15;
            if (bx == 0) {
#pragma unroll
                for (int r = 0; r < 4; ++r) {
                    int m = by * 128 + wm + mt * 16 + quad * 4 + r;
                    int b = m >> 11, s = m & 2047;
                    kc_ws[(((size_t)b * H_ + h) * S_ + s) * DK_ + n] = (bf16)acc[mt][nt][r];
                }
            } else {
                int m0 = by * 128 + wm + mt * 16 + quad * 4;   // r=0..3 consecutive s
                int b = m0 >> 11, s = m0 & 2047;
                bfx4 pack;
#pragma unroll
                for (int r = 0; r < 4; ++r) pack[r] = (bf16)acc[mt][nt][r];
                *(bfx4*)(&vt_ws[(((size_t)b * H_ + h) * DVP_ + n) * S_ + s]) = pack;
            }
        }
}

// ----------------------------------------------------------------------------
// Flash-style causal attention v2 (MFMA). Block = 64 q rows x 4 waves.
// No max-stabilization (scores provably bounded, softmax shift-invariant).
// Row-sum l via ones-column of padded V^T (9th accumulator tile).
// LDS: K only (25.6 KB) + P (9 KB) -> 4 blocks/CU. 2 barriers/iter.
// OUTPUT FLOAT32. grid (32, 32)
// ----------------------------------------------------------------------------
#define KSTR 200
#define PSTR 72

__global__ __launch_bounds__(256, 4) void k_attn(
    const bf16* __restrict__ q_ws, const bf16* __restrict__ kc_ws,
    const bf16* __restrict__ kr_ws, const bf16* __restrict__ vt_ws,
    float* __restrict__ out) {
    __shared__ __attribute__((aligned(16))) bf16 K_lds[64 * KSTR];
    __shared__ __attribute__((aligned(16))) bf16 P_lds[4 * 16 * PSTR];
    int qt = 31 - blockIdx.x;       // long blocks first
    int bh = blockIdx.y;
    int b = bh >> 4, h = bh & 15;
    int q0 = qt * 64;
    int tid = threadIdx.x, wave = tid >> 6, lane = tid & 63;
    int l15 = lane & 15, quad = lane >> 4;

    const bf16* qrow = q_ws + ((size_t)bh * S_ + q0 + wave * 16 + l15) * DQK_;
    bfx8 qf[6];
#pragma unroll
    for (int ks = 0; ks < 6; ++ks)
        qf[ks] = *(const bfx8*)(qrow + ks * 32 + quad * 8);

    floatx4 o_acc[9];
#pragma unroll
    for (int vt = 0; vt < 9; ++vt) o_acc[vt] = (floatx4){0.f, 0.f, 0.f, 0.f};

    const bf16* vbase = vt_ws + (size_t)bh * DVP_ * S_;
    int ntiles = qt + 1;
    for (int t = 0; t < ntiles; ++t) {
        int kv0 = t * 64;
        __syncthreads();   // prior iteration's K_lds reads complete
        {   // stage K tile: k_c cols 0..127, k_r cols 128..191
            const bf16* src = kc_ws + ((size_t)bh * S_ + kv0) * DK_;
#pragma unroll
            for (int i = 0; i < 4; ++i) {
                int flat = (i * 256 + tid) * 8;
                int n = flat >> 7, cc = flat & 127;
                *(bfx8*)(&K_lds[n * KSTR + cc]) = *(const bfx8*)(src + (size_t)n * DK_ + cc);
            }
            const bf16* srk = kr_ws + ((size_t)b * S_ + kv0) * DR_;
#pragma unroll
            for (int i = 0; i < 2; ++i) {
                int flat = (i * 256 + tid) * 8;
                int n = flat >> 6, cc = flat & 63;
                *(bfx8*)(&K_lds[n * KSTR + 128 + cc]) = *(const bfx8*)(srk + (size_t)n * DR_ + cc);
            }
        }
        __syncthreads();

        // scores (already in exp2 domain: q pre-scaled by C1)
        floatx4 sc[4];
#pragma unroll
        for (int nt = 0; nt < 4; ++nt) sc[nt] = (floatx4){0.f, 0.f, 0.f, 0.f};
#pragma unroll
        for (int ks = 0; ks < 6; ++ks)
#pragma unroll
            for (int nt = 0; nt < 4; ++nt) {
                bfx8 kf = *(const bfx8*)(&K_lds[(nt * 16 + l15) * KSTR + ks * 32 + quad * 8]);
                sc[nt] = __builtin_amdgcn_mfma_f32_16x16x32_bf16(qf[ks], kf, sc[nt], 0, 0, 0);
            }
        if (t == ntiles - 1) {   // diagonal tile causal mask
#pragma unroll
            for (int nt = 0; nt < 4; ++nt)
#pragma unroll
                for (int r = 0; r < 4; ++r) {
                    int n_g = kv0 + nt * 16 + l15;
                    int q_g = q0 + wave * 16 + quad * 4 + r;
                    if (n_g > q_g) sc[nt][r] = MASK_VAL;
                }
        }
        // P = exp2(sc), straight to LDS (C-layout -> A-layout round trip;
        // wave-private region, same-wave DS ordering: no barrier needed)
#pragma unroll
        for (int nt = 0; nt < 4; ++nt)
#pragma unroll
            for (int r = 0; r < 4; ++r)
                P_lds[(wave * 16 + quad * 4 + r) * PSTR + nt * 16 + l15] =
                    (bf16)exp2f(sc[nt][r]);
        // O += P @ V ; V^T fragments straight from global (L2-resident);
        // tile 8 is the ones-column -> accumulates row sums l.
#pragma unroll
        for (int ks2 = 0; ks2 < 2; ++ks2) {
            bfx8 pf = *(const bfx8*)(&P_lds[(wave * 16 + l15) * PSTR + ks2 * 32 + quad * 8]);
#pragma unroll
            for (int vt = 0; vt < 9; ++vt) {
                bfx8 vf = *(const bfx8*)(vbase + (size_t)(vt * 16 + l15) * S_ +
                                         kv0 + ks2 * 32 + quad * 8);
                o_acc[vt] = __builtin_amdgcn_mfma_f32_16x16x32_bf16(pf, vf, o_acc[vt], 0, 0, 0);
            }
        }
    }
    // epilogue: l lives in o_acc[8] col 128 (lanes l15==0); broadcast per quad
    float rinv[4];
#pragma unroll
    for (int r = 0; r < 4; ++r)
        rinv[r] = 1.f / __shfl(o_acc[8][r], lane & 48);
#pragma unroll
    for (int vt = 0; vt < 8; ++vt)
#pragma unroll
        for (int r = 0; r < 4; ++r) {
            int s = q0 + wave * 16 + quad * 4 + r;
            int v = vt * 16 + l15;
            out[((size_t)b * S_ + s) * (H_ * DV_) + h * DV_ + v] = o_acc[vt][r] * rinv[r];
        }
}

// ----------------------------------------------------------------------------
extern "C" void kernel_launch(void* const* d_in, const int* in_sizes, int n_in,
                              void* d_out, int out_size, void* d_ws, size_t ws_size,
                              hipStream_t stream) {
    const float* x    = (const float*)d_in[0];
    const float* W_c  = (const float*)d_in[1];
    const float* W_cp = (const float*)d_in[2];
    const float* W_qc = (const float*)d_in[3];
    const float* W_qr = (const float*)d_in[4];
    const float* W_kc = (const float*)d_in[5];
    const float* W_kr = (const float*)d_in[6];
    const float* W_v  = (const float*)d_in[7];
    float* out = (float*)d_out;

    // c/cp (12 MB bf16) live only between G1 and G3/G2; host in d_out (33.5 MB f32).
    bf16* c_ws  = (bf16*)d_out;
    bf16* cp_ws = (bf16*)d_out + (size_t)B_ * S_ * DC_;

    char* ws = (char*)d_ws;
    size_t off = 0;
    auto alloc = [&](size_t elems) { bf16* p = (bf16*)(ws + off); off += elems * sizeof(bf16); return p; };
    bf16* Wt_c  = alloc((size_t)DIM_ * DC_);
    bf16* Wt_cp = alloc((size_t)DIM_ * DCP_);
    bf16* Wt_qc = alloc((size_t)H_ * DCP_ * DK_);
    bf16* Wt_qr = alloc((size_t)H_ * DCP_ * DR_);
    bf16* Wt_kc = alloc((size_t)H_ * DC_ * DK_);
    bf16* Wt_kr = alloc((size_t)DIM_ * DR_);
    bf16* Wt_v  = alloc((size_t)H_ * DC_ * DV_);
    bf16* kr_ws = alloc((size_t)B_ * S_ * DR_);
    bf16* q_ws  = alloc((size_t)B_ * H_ * S_ * DQK_);
    bf16* kc_ws = alloc((size_t)B_ * H_ * S_ * DK_);
    bf16* vt_ws = alloc((size_t)B_ * H_ * DVP_ * S_);

    k_vinit<<<dim3(512), 256, 0, stream>>>(vt_ws);
    k_transpose<<<dim3(DC_ / 32, DIM_ / 32, 1),  256, 0, stream>>>(W_c,  Wt_c,  DIM_, DC_);
    k_transpose<<<dim3(DCP_ / 32, DIM_ / 32, 1), 256, 0, stream>>>(W_cp, Wt_cp, DIM_, DCP_);
    k_transpose<<<dim3(DK_ / 32, DCP_ / 32, H_), 256, 0, stream>>>(W_qc, Wt_qc, DCP_, DK_);
    k_transpose<<<dim3(DR_ / 32, DCP_ / 32, H_), 256, 0, stream>>>(W_qr, Wt_qr, DCP_, DR_);
    k_transpose<<<dim3(DK_ / 32, DC_ / 32, H_),  256, 0, stream>>>(W_kc, Wt_kc, DC_, DK_);
    k_transpose<<<dim3(DR_ / 32, DIM_ / 32, 1),  256, 0, stream>>>(W_kr, Wt_kr, DIM_, DR_);
    k_transpose<<<dim3(DV_ / 32, DC_ / 32, H_),  256, 0, stream>>>(W_v,  Wt_v,  DC_, DV_);

    k_gemm1<<<dim3(13, 32), 256, 0, stream>>>(x, Wt_c, Wt_cp, Wt_kr, c_ws, cp_ws, kr_ws);
    k_gemm2<<<dim3(2, 32, H_), 256, 0, stream>>>(cp_ws, Wt_qc, Wt_qr, q_ws);
    k_gemm3<<<dim3(2, 32, H_), 256, 0, stream>>>(c_ws, Wt_kc, Wt_v, kc_ws, vt_ws);
    k_attn<<<dim3(32, B_ * H_), 256, 0, stream>>>(q_ws, kc_ws, kr_ws, vt_ws, out);
}

// Round 8
// 331.434 us; speedup vs baseline: 1.9437x; 1.9437x over previous
//
#include <hip/hip_runtime.h>
#include <stdint.h>

typedef __bf16 bf16;
typedef __bf16 bfx8 __attribute__((ext_vector_type(8)));
typedef __bf16 bfx4 __attribute__((ext_vector_type(4)));
typedef float floatx4 __attribute__((ext_vector_type(4)));

#define B_ 2
#define S_ 2048
#define DIM_ 2048
#define H_ 16
#define DK_ 128
#define DR_ 64
#define DC_ 512
#define DCP_ 1024
#define DV_ 128
#define DQK_ 192

#define MASK_VAL (-30000.0f)
#define C1_ 0.10411754f   // (1/sqrt(192)) * log2(e), folded into q at G2

// ----------------------------------------------------------------------------
// x f32 -> bf16 cast (exact grid: 8.4M elems / 8 per thread / 256 = 4096 blocks)
// ----------------------------------------------------------------------------
__global__ void k_cast(const float* __restrict__ in, bf16* __restrict__ out) {
    size_t i = ((size_t)blockIdx.x * 256 + threadIdx.x) * 8;
    float4 a = *(const float4*)(in + i);
    float4 b = *(const float4*)(in + i + 4);
    bfx8 r;
    r[0] = (bf16)a.x; r[1] = (bf16)a.y; r[2] = (bf16)a.z; r[3] = (bf16)a.w;
    r[4] = (bf16)b.x; r[5] = (bf16)b.y; r[6] = (bf16)b.z; r[7] = (bf16)b.w;
    *(bfx8*)(out + i) = r;
}

// ----------------------------------------------------------------------------
// Batched transpose + downcast: in f32 [Hb][K][N] -> out bf16 [Hb][N][K]
// ----------------------------------------------------------------------------
__global__ void k_transpose(const float* __restrict__ in, bf16* __restrict__ out,
                            int K, int N) {
    __shared__ float tile[32][33];
    int h = blockIdx.z;
    int n0 = blockIdx.x * 32, k0 = blockIdx.y * 32;
    const float* ip = in + (size_t)h * K * N;
    bf16* op = out + (size_t)h * K * N;
    int tx = threadIdx.x & 31, ty = threadIdx.x >> 5;
#pragma unroll
    for (int i = 0; i < 32; i += 8)
        tile[ty + i][tx] = ip[(size_t)(k0 + ty + i) * N + (n0 + tx)];
    __syncthreads();
#pragma unroll
    for (int i = 0; i < 32; i += 8)
        op[(size_t)(n0 + ty + i) * K + (k0 + tx)] = (bf16)tile[tx][ty + i];
}

// ----------------------------------------------------------------------------
// GEMM core v2 (m97 recipe): global_load_lds width-16 staging into
// XOR-swizzled [128][32] LDS tiles (8 KB each). Element (row, k) lives at
// row*32 + pb*8 + (k&7), pb = (k>>3) ^ ((row>>1)&3)  -> conflict-free b128
// fragment reads; LDS dest of each 1 KB chunk stays linear (HW: base+lane*16).
// ----------------------------------------------------------------------------
__device__ __forceinline__ void gld16(const bf16* g, bf16* l) {
    __builtin_amdgcn_global_load_lds(
        (const __attribute__((address_space(1))) void*)g,
        (__attribute__((address_space(3))) void*)l, 16, 0, 0);
}

__device__ __forceinline__ bfx8 frag_ld(const bf16* lds, int row, int quad) {
    int pb = quad ^ ((row >> 1) & 3);
    return *(const bfx8*)(lds + row * 32 + pb * 8);
}

__device__ __forceinline__ void gemm_core(const bf16* __restrict__ A,
                                          const bf16* __restrict__ Bt,
                                          int K, int rowlimB,
                                          floatx4 acc[4][4],
                                          bf16* A_lds, bf16* B_lds) {
    int tid = threadIdx.x, wave = tid >> 6, lane = tid & 63;
    int l15 = lane & 15, quad = lane >> 4;
    int wm = (wave & 1) * 64, wn = (wave >> 1) * 64;
    // staging: chunk c = wave*2 + {0,1}; lane covers (row = 16c + lane/4,
    // k-block kb = (lane&3) ^ ((row>>1)&3)) -> LDS linear pos c*512 + lane*8.
    int ch0 = wave * 2, ch1 = wave * 2 + 1;
    int r0 = ch0 * 16 + (lane >> 2), r1 = ch1 * 16 + (lane >> 2);
    int kb0 = (lane & 3) ^ ((r0 >> 1) & 3), kb1 = (lane & 3) ^ ((r1 >> 1) & 3);
    int rb0 = r0 <= rowlimB ? r0 : rowlimB;
    int rb1 = r1 <= rowlimB ? r1 : rowlimB;
    const bf16* a0 = A + (size_t)r0 * K + kb0 * 8;
    const bf16* a1 = A + (size_t)r1 * K + kb1 * 8;
    const bf16* b0 = Bt + (size_t)rb0 * K + kb0 * 8;
    const bf16* b1 = Bt + (size_t)rb1 * K + kb1 * 8;
    bf16* da0 = A_lds + ch0 * 512;  // wave-uniform dest bases
    bf16* da1 = A_lds + ch1 * 512;
    bf16* db0 = B_lds + ch0 * 512;
    bf16* db1 = B_lds + ch1 * 512;
    for (int k0 = 0; k0 < K; k0 += 32) {
        __syncthreads();            // prior iteration's fragment reads done
        gld16(a0 + k0, da0);
        gld16(a1 + k0, da1);
        gld16(b0 + k0, db0);
        gld16(b1 + k0, db1);
        __syncthreads();            // staging complete (vmcnt drained)
        bfx8 a[4], b[4];
#pragma unroll
        for (int t = 0; t < 4; ++t) a[t] = frag_ld(A_lds, wm + t * 16 + l15, quad);
#pragma unroll
        for (int t = 0; t < 4; ++t) b[t] = frag_ld(B_lds, wn + t * 16 + l15, quad);
#pragma unroll
        for (int mt = 0; mt < 4; ++mt)
#pragma unroll
            for (int nt = 0; nt < 4; ++nt)
                acc[mt][nt] = __builtin_amdgcn_mfma_f32_16x16x32_bf16(
                    a[mt], b[nt], acc[mt][nt], 0, 0, 0);
    }
}

// G1: xb -> {c, cp, k_r} (bf16).  grid (13, 32)
__global__ __launch_bounds__(256, 3) void k_gemm1(
    const bf16* __restrict__ xb, const bf16* __restrict__ Wt_c,
    const bf16* __restrict__ Wt_cp, const bf16* __restrict__ Wt_kr,
    bf16* __restrict__ c_ws, bf16* __restrict__ cp_ws, bf16* __restrict__ kr_ws) {
    __shared__ __attribute__((aligned(16))) bf16 A_lds[128 * 32];
    __shared__ __attribute__((aligned(16))) bf16 B_lds[128 * 32];
    int bx = blockIdx.x, by = blockIdx.y;
    const bf16* Bt; bf16* outp; int ldc, col0, rowlim;
    if (bx < 4)       { Bt = Wt_c  + (size_t)bx * 128 * DIM_;       outp = c_ws;  ldc = DC_;  col0 = bx * 128;       rowlim = 127; }
    else if (bx < 12) { Bt = Wt_cp + (size_t)(bx - 4) * 128 * DIM_; outp = cp_ws; ldc = DCP_; col0 = (bx - 4) * 128; rowlim = 127; }
    else              { Bt = Wt_kr;                                  outp = kr_ws; ldc = DR_;  col0 = 0;              rowlim = 63;  }
    floatx4 acc[4][4];
#pragma unroll
    for (int i = 0; i < 4; ++i)
#pragma unroll
        for (int j = 0; j < 4; ++j) acc[i][j] = (floatx4){0.f, 0.f, 0.f, 0.f};
    gemm_core(xb + (size_t)by * 128 * DIM_, Bt, DIM_, rowlim, acc, A_lds, B_lds);
    int tid = threadIdx.x, wave = tid >> 6, lane = tid & 63;
    int l15 = lane & 15, quad = lane >> 4;
    int wm = (wave & 1) * 64, wn = (wave >> 1) * 64;
#pragma unroll
    for (int mt = 0; mt < 4; ++mt)
#pragma unroll
        for (int nt = 0; nt < 4; ++nt) {
            int n = wn + nt * 16 + l15;
            if (n > rowlim) continue;
#pragma unroll
            for (int r = 0; r < 4; ++r) {
                int m = by * 128 + wm + mt * 16 + quad * 4 + r;
                outp[(size_t)m * ldc + col0 + n] = (bf16)acc[mt][nt][r];
            }
        }
}

// G2: cp -> q*C1 (q_c cols 0..127, q_r cols 128..191), per head. grid (2, 32, 16)
__global__ __launch_bounds__(256, 3) void k_gemm2(
    const bf16* __restrict__ cp_ws, const bf16* __restrict__ Wt_qc,
    const bf16* __restrict__ Wt_qr, bf16* __restrict__ q_ws) {
    __shared__ __attribute__((aligned(16))) bf16 A_lds[128 * 32];
    __shared__ __attribute__((aligned(16))) bf16 B_lds[128 * 32];
    int bx = blockIdx.x, by = blockIdx.y, h = blockIdx.z;
    const bf16* Bt; int col0, rowlim;
    if (bx == 0) { Bt = Wt_qc + (size_t)h * DK_ * DCP_; col0 = 0;   rowlim = 127; }
    else         { Bt = Wt_qr + (size_t)h * DR_ * DCP_; col0 = 128; rowlim = 63;  }
    floatx4 acc[4][4];
#pragma unroll
    for (int i = 0; i < 4; ++i)
#pragma unroll
        for (int j = 0; j < 4; ++j) acc[i][j] = (floatx4){0.f, 0.f, 0.f, 0.f};
    gemm_core(cp_ws + (size_t)by * 128 * DCP_, Bt, DCP_, rowlim, acc, A_lds, B_lds);
    int tid = threadIdx.x, wave = tid >> 6, lane = tid & 63;
    int l15 = lane & 15, quad = lane >> 4;
    int wm = (wave & 1) * 64, wn = (wave >> 1) * 64;
#pragma unroll
    for (int mt = 0; mt < 4; ++mt)
#pragma unroll
        for (int nt = 0; nt < 4; ++nt) {
            int n = wn + nt * 16 + l15;
            if (n > rowlim) continue;
#pragma unroll
            for (int r = 0; r < 4; ++r) {
                int m = by * 128 + wm + mt * 16 + quad * 4 + r;
                int b = m >> 11, s = m & 2047;
                q_ws[(((size_t)b * H_ + h) * S_ + s) * DQK_ + col0 + n] =
                    (bf16)(acc[mt][nt][r] * C1_);
            }
        }
}

// G3: c -> {k_c [B,H,S,128], v^T [B,H,128,S]}, per head. grid (2,32,16)
__global__ __launch_bounds__(256, 3) void k_gemm3(
    const bf16* __restrict__ c_ws, const bf16* __restrict__ Wt_kc,
    const bf16* __restrict__ Wt_v, bf16* __restrict__ kc_ws, bf16* __restrict__ vt_ws) {
    __shared__ __attribute__((aligned(16))) bf16 A_lds[128 * 32];
    __shared__ __attribute__((aligned(16))) bf16 B_lds[128 * 32];
    int bx = blockIdx.x, by = blockIdx.y, h = blockIdx.z;
    const bf16* Bt = (bx == 0) ? (Wt_kc + (size_t)h * DK_ * DC_)
                               : (Wt_v  + (size_t)h * DV_ * DC_);
    floatx4 acc[4][4];
#pragma unroll
    for (int i = 0; i < 4; ++i)
#pragma unroll
        for (int j = 0; j < 4; ++j) acc[i][j] = (floatx4){0.f, 0.f, 0.f, 0.f};
    gemm_core(c_ws + (size_t)by * 128 * DC_, Bt, DC_, 127, acc, A_lds, B_lds);
    int tid = threadIdx.x, wave = tid >> 6, lane = tid & 63;
    int l15 = lane & 15, quad = lane >> 4;
    int wm = (wave & 1) * 64, wn = (wave >> 1) * 64;
#pragma unroll
    for (int mt = 0; mt < 4; ++mt)
#pragma unroll
        for (int nt = 0; nt < 4; ++nt) {
            int n = wn + nt * 16 + l15;
            if (bx == 0) {
#pragma unroll
                for (int r = 0; r < 4; ++r) {
                    int m = by * 128 + wm + mt * 16 + quad * 4 + r;
                    int b = m >> 11, s = m & 2047;
                    kc_ws[(((size_t)b * H_ + h) * S_ + s) * DK_ + n] = (bf16)acc[mt][nt][r];
                }
            } else {
                int m0 = by * 128 + wm + mt * 16 + quad * 4;   // r=0..3 consecutive s
                int b = m0 >> 11, s = m0 & 2047;
                bfx4 pack;
#pragma unroll
                for (int r = 0; r < 4; ++r) pack[r] = (bf16)acc[mt][nt][r];
                *(bfx4*)(&vt_ws[(((size_t)b * H_ + h) * DV_ + n) * S_ + s]) = pack;
            }
        }
}

// ----------------------------------------------------------------------------
// Flash attention v3. Block = pair of 64-row Q tiles (qt = 31-p, then p):
// every block does exactly 33 K-iters -> perfect balance (512 blocks, 2/CU).
// K & V staged in LDS via register prefetch (next tile's global loads issued
// right after the staging barrier -> latency hidden under MFMA/exp2).
// No max-stabilization; l via constant ones B-fragment (9th acc tile).
// OUTPUT FLOAT32. grid (16, 32)
// ----------------------------------------------------------------------------
#define KSTR 200
#define VSTR 72
#define PSTR 72

__global__ __launch_bounds__(256, 2) void k_attn(
    const bf16* __restrict__ q_ws, const bf16* __restrict__ kc_ws,
    const bf16* __restrict__ kr_ws, const bf16* __restrict__ vt_ws,
    float* __restrict__ out) {
    __shared__ __attribute__((aligned(16))) bf16 K_lds[64 * KSTR];   // 25.0 KB
    __shared__ __attribute__((aligned(16))) bf16 V_lds[128 * VSTR];  // 18.0 KB
    __shared__ __attribute__((aligned(16))) bf16 P_lds[64 * PSTR];   // 9.0 KB
    int p = blockIdx.x;
    int bh = blockIdx.y, b = bh >> 4, h = bh & 15;
    int tid = threadIdx.x, wave = tid >> 6, lane = tid & 63;
    int l15 = lane & 15, quad = lane >> 4;

    // constant ones B-fragment: B[k][n] = 1 iff n==0  (row-sum column)
    bf16 ov = (bf16)(l15 == 0 ? 1.f : 0.f);
    bfx8 ones8 = {ov, ov, ov, ov, ov, ov, ov, ov};

    // per-thread staging roles (constant across iterations)
    int kn[4], kcc[4], rn[2], rcc[2], vr[4], vcc[4];
#pragma unroll
    for (int i = 0; i < 4; ++i) { int f = (i * 256 + tid) * 8; kn[i] = f >> 7; kcc[i] = f & 127; }
#pragma unroll
    for (int i = 0; i < 2; ++i) { int f = (i * 256 + tid) * 8; rn[i] = f >> 6; rcc[i] = f & 63; }
#pragma unroll
    for (int i = 0; i < 4; ++i) { int f = (i * 256 + tid) * 8; vr[i] = f >> 6; vcc[i] = f & 63; }
    const bf16* kcp[4]; const bf16* krp[2]; const bf16* vp[4];
#pragma unroll
    for (int i = 0; i < 4; ++i) kcp[i] = kc_ws + ((size_t)bh * S_ + kn[i]) * DK_ + kcc[i];
#pragma unroll
    for (int i = 0; i < 2; ++i) krp[i] = kr_ws + ((size_t)b * S_ + rn[i]) * DR_ + rcc[i];
#pragma unroll
    for (int i = 0; i < 4; ++i) vp[i] = vt_ws + ((size_t)bh * DV_ + vr[i]) * S_ + vcc[i];

    for (int ph = 0; ph < 2; ++ph) {
        int qt = ph ? p : 31 - p;
        int q0 = qt * 64, ntiles = qt + 1;

        const bf16* qrow = q_ws + ((size_t)bh * S_ + q0 + wave * 16 + l15) * DQK_;
        bfx8 qf[6];
#pragma unroll
        for (int ks = 0; ks < 6; ++ks)
            qf[ks] = *(const bfx8*)(qrow + ks * 32 + quad * 8);

        floatx4 o_acc[9];
#pragma unroll
        for (int vt = 0; vt < 9; ++vt) o_acc[vt] = (floatx4){0.f, 0.f, 0.f, 0.f};

        // prefetch tile 0 into registers
        bfx8 pk[4], pr[2], pv[4];
#pragma unroll
        for (int i = 0; i < 4; ++i) pk[i] = *(const bfx8*)(kcp[i]);
#pragma unroll
        for (int i = 0; i < 2; ++i) pr[i] = *(const bfx8*)(krp[i]);
#pragma unroll
        for (int i = 0; i < 4; ++i) pv[i] = *(const bfx8*)(vp[i]);

        for (int t = 0; t < ntiles; ++t) {
            __syncthreads();   // prior iteration's LDS reads complete
#pragma unroll
            for (int i = 0; i < 4; ++i) *(bfx8*)(&K_lds[kn[i] * KSTR + kcc[i]]) = pk[i];
#pragma unroll
            for (int i = 0; i < 2; ++i) *(bfx8*)(&K_lds[rn[i] * KSTR + 128 + rcc[i]]) = pr[i];
#pragma unroll
            for (int i = 0; i < 4; ++i) *(bfx8*)(&V_lds[vr[i] * VSTR + vcc[i]]) = pv[i];
            __syncthreads();   // staging visible
            // issue next tile's global loads (latency hidden under compute)
            if (t + 1 < ntiles) {
                size_t kv1 = (size_t)(t + 1) * 64;
#pragma unroll
                for (int i = 0; i < 4; ++i) pk[i] = *(const bfx8*)(kcp[i] + kv1 * DK_);
#pragma unroll
                for (int i = 0; i < 2; ++i) pr[i] = *(const bfx8*)(krp[i] + kv1 * DR_);
#pragma unroll
                for (int i = 0; i < 4; ++i) pv[i] = *(const bfx8*)(vp[i] + kv1);
            }
            // scores (exp2 domain: q pre-scaled by C1)
            floatx4 sc[4];
#pragma unroll
            for (int nt = 0; nt < 4; ++nt) sc[nt] = (floatx4){0.f, 0.f, 0.f, 0.f};
#pragma unroll
            for (int ks = 0; ks < 6; ++ks)
#pragma unroll
                for (int nt = 0; nt < 4; ++nt) {
                    bfx8 kf = *(const bfx8*)(&K_lds[(nt * 16 + l15) * KSTR + ks * 32 + quad * 8]);
                    sc[nt] = __builtin_amdgcn_mfma_f32_16x16x32_bf16(qf[ks], kf, sc[nt], 0, 0, 0);
                }
            if (t == ntiles - 1) {   // diagonal tile causal mask
                int kv0 = t * 64;
#pragma unroll
                for (int nt = 0; nt < 4; ++nt)
#pragma unroll
                    for (int r = 0; r < 4; ++r) {
                        int n_g = kv0 + nt * 16 + l15;
                        int q_g = q0 + wave * 16 + quad * 4 + r;
                        if (n_g > q_g) sc[nt][r] = MASK_VAL;
                    }
            }
            // P = exp2(sc) -> LDS (wave-private C->A layout round trip)
#pragma unroll
            for (int nt = 0; nt < 4; ++nt)
#pragma unroll
                for (int r = 0; r < 4; ++r)
                    P_lds[(wave * 16 + quad * 4 + r) * PSTR + nt * 16 + l15] =
                        (bf16)exp2f(sc[nt][r]);
            // O += P @ V ; tile 8 = ones column -> row sums l
#pragma unroll
            for (int ks2 = 0; ks2 < 2; ++ks2) {
                bfx8 pf = *(const bfx8*)(&P_lds[(wave * 16 + l15) * PSTR + ks2 * 32 + quad * 8]);
#pragma unroll
                for (int vt = 0; vt < 8; ++vt) {
                    bfx8 vf = *(const bfx8*)(&V_lds[(vt * 16 + l15) * VSTR + ks2 * 32 + quad * 8]);
                    o_acc[vt] = __builtin_amdgcn_mfma_f32_16x16x32_bf16(pf, vf, o_acc[vt], 0, 0, 0);
                }
                o_acc[8] = __builtin_amdgcn_mfma_f32_16x16x32_bf16(pf, ones8, o_acc[8], 0, 0, 0);
            }
        }
        // epilogue: l in o_acc[8] col 0 (lanes l15==0); broadcast per quad
        float rinv[4];
#pragma unroll
        for (int r = 0; r < 4; ++r)
            rinv[r] = 1.f / __shfl(o_acc[8][r], lane & 48);
#pragma unroll
        for (int vt = 0; vt < 8; ++vt)
#pragma unroll
            for (int r = 0; r < 4; ++r) {
                int s = q0 + wave * 16 + quad * 4 + r;
                int v = vt * 16 + l15;
                out[((size_t)b * S_ + s) * (H_ * DV_) + h * DV_ + v] = o_acc[vt][r] * rinv[r];
            }
    }
}

// ----------------------------------------------------------------------------
extern "C" void kernel_launch(void* const* d_in, const int* in_sizes, int n_in,
                              void* d_out, int out_size, void* d_ws, size_t ws_size,
                              hipStream_t stream) {
    const float* x    = (const float*)d_in[0];
    const float* W_c  = (const float*)d_in[1];
    const float* W_cp = (const float*)d_in[2];
    const float* W_qc = (const float*)d_in[3];
    const float* W_qr = (const float*)d_in[4];
    const float* W_kc = (const float*)d_in[5];
    const float* W_kr = (const float*)d_in[6];
    const float* W_v  = (const float*)d_in[7];
    float* out = (float*)d_out;

    // d_out (33.5 MB f32) hosts transient bf16 buffers: c 4.2 + cp 8.4 + xb 16.8
    // = 29.4 MB, all dead before k_attn overwrites out.
    bf16* c_ws  = (bf16*)d_out;
    bf16* cp_ws = c_ws + (size_t)B_ * S_ * DC_;
    bf16* xb    = cp_ws + (size_t)B_ * S_ * DCP_;

    char* ws = (char*)d_ws;
    size_t off = 0;
    auto alloc = [&](size_t elems) { bf16* p = (bf16*)(ws + off); off += elems * sizeof(bf16); return p; };
    bf16* Wt_c  = alloc((size_t)DIM_ * DC_);
    bf16* Wt_cp = alloc((size_t)DIM_ * DCP_);
    bf16* Wt_qc = alloc((size_t)H_ * DCP_ * DK_);
    bf16* Wt_qr = alloc((size_t)H_ * DCP_ * DR_);
    bf16* Wt_kc = alloc((size_t)H_ * DC_ * DK_);
    bf16* Wt_kr = alloc((size_t)DIM_ * DR_);
    bf16* Wt_v  = alloc((size_t)H_ * DC_ * DV_);
    bf16* kr_ws = alloc((size_t)B_ * S_ * DR_);
    bf16* q_ws  = alloc((size_t)B_ * H_ * S_ * DQK_);
    bf16* kc_ws = alloc((size_t)B_ * H_ * S_ * DK_);
    bf16* vt_ws = alloc((size_t)B_ * H_ * DV_ * S_);

    k_cast<<<dim3(4096), 256, 0, stream>>>(x, xb);
    k_transpose<<<dim3(DC_ / 32, DIM_ / 32, 1),  256, 0, stream>>>(W_c,  Wt_c,  DIM_, DC_);
    k_transpose<<<dim3(DCP_ / 32, DIM_ / 32, 1), 256, 0, stream>>>(W_cp, Wt_cp, DIM_, DCP_);
    k_transpose<<<dim3(DK_ / 32, DCP_ / 32, H_), 256, 0, stream>>>(W_qc, Wt_qc, DCP_, DK_);
    k_transpose<<<dim3(DR_ / 32, DCP_ / 32, H_), 256, 0, stream>>>(W_qr, Wt_qr, DCP_, DR_);
    k_transpose<<<dim3(DK_ / 32, DC_ / 32, H_),  256, 0, stream>>>(W_kc, Wt_kc, DC_, DK_);
    k_transpose<<<dim3(DR_ / 32, DIM_ / 32, 1),  256, 0, stream>>>(W_kr, Wt_kr, DIM_, DR_);
    k_transpose<<<dim3(DV_ / 32, DC_ / 32, H_),  256, 0, stream>>>(W_v,  Wt_v,  DC_, DV_);

    k_gemm1<<<dim3(13, 32), 256, 0, stream>>>(xb, Wt_c, Wt_cp, Wt_kr, c_ws, cp_ws, kr_ws);
    k_gemm2<<<dim3(2, 32, H_), 256, 0, stream>>>(cp_ws, Wt_qc, Wt_qr, q_ws);
    k_gemm3<<<dim3(2, 32, H_), 256, 0, stream>>>(c_ws, Wt_kc, Wt_v, kc_ws, vt_ws);
    k_attn<<<dim3(16, B_ * H_), 256, 0, stream>>>(q_ws, kc_ws, kr_ws, vt_ws, out);
}